// Round 3
// baseline (386.503 us; speedup 1.0000x reference)
//
#include <hip/hip_runtime.h>
#include <cstddef>
#include <cstdint>

#define THRESH 0.8f
#define DECAY  0.2f

typedef unsigned short ushort_t;
typedef __attribute__((ext_vector_type(8))) short bf16x8;
typedef __attribute__((ext_vector_type(4))) float f32x4;
typedef __attribute__((ext_vector_type(4))) int i32x4;   // also 16 x i8 operand

__device__ __forceinline__ ushort_t f2bf(float f) {
    union { float f; unsigned u; } v; v.f = f;
    unsigned r = v.u + 0x7FFFu + ((v.u >> 16) & 1u);
    return (ushort_t)(r >> 16);
}
__device__ __forceinline__ float bf2f(ushort_t h) {
    union { unsigned u; float f; } v; v.u = ((unsigned)h) << 16;
    return v.f;
}
__device__ __forceinline__ float blo(unsigned u) {
    union { unsigned x; float f; } v; v.x = u << 16; return v.f;
}
__device__ __forceinline__ float bhi(unsigned u) {
    union { unsigned x; float f; } v; v.x = u & 0xFFFF0000u; return v.f;
}

// async global->LDS, 16B per lane; LDS dest = wave-uniform base + lane*16
__device__ __forceinline__ void gload16(const void* g, void* l) {
    __builtin_amdgcn_global_load_lds(
        (const __attribute__((address_space(1))) void*)g,
        (__attribute__((address_space(3))) void*)l,
        16, 0, 0);
}

// inline-asm LDS read: keeps waitcnt control OUT of the compiler (it cannot
// see these as LDS ops, so it cannot insert vmcnt(0)/lgkmcnt for them).
// Rule #18: every consuming MFMA cluster is fenced by explicit
// "s_waitcnt lgkmcnt(0)" + sched_barrier(0).
#define DSREAD(dst, addr, off) \
    asm volatile("ds_read_b128 %0, %1 offset:" #off : "=v"(dst) : "v"(addr))

#define MM(i, j, a, w) \
    acc[i][j] = __builtin_amdgcn_mfma_f32_16x16x32_bf16(a, w, acc[i][j], 0, 0, 0)

// ---------------------------------------------------------------------------
// Currents GEMM, v3: true 8-phase schedule (T2+T3+T4+T5, m194-m201 template).
//   A' = [Ah | Ah | Al] (10240 x 1536), W' = [Wh | Wl | Wh] (3072 x 1536)
//   => A'.W'^T == Ah.Wh + Ah.Wl + Al.Wh  (3-term near-fp32 split).
// 256x256 tile, BK=32, 8 waves (2Mx4N, per-wave 128x64), 4 LDS buffers
// (4 x 32KB), prefetch distance 2 tiles.  Per K-tile: 2 phases
//   phase A: asm ds_read af[0..3](ih=0) + wf[0..3]; stage A-halves of t+2;
//            s_barrier; lgkmcnt(0)+sched_barrier; setprio(1); 16 MFMA; bar.
//   phase B: asm ds_read af[0..3](ih=1); stage B-halves of t+2;
//            vmcnt(4) [oldest tile landed, rest IN FLIGHT]; s_barrier;
//            lgkmcnt(0)+sched_barrier; setprio(1); 16 MFMA; bar.
// vmcnt ledger: prologue stages t0,t1 (8 loads), vmcnt(4)+bar -> t0 ready.
// Steady state: 2+2 loads issued/tile, vmcnt(4) waits oldest tile, next
// tile's reads are after the barrier -> collective safety.  Tail: tile 46
// drains vmcnt(0), tile 47 reads only.
// ---------------------------------------------------------------------------
__global__ __launch_bounds__(512, 2) void cur_gemm_8ph(
    const ushort_t* __restrict__ A, const ushort_t* __restrict__ W,
    const float* __restrict__ bias, float* __restrict__ C)
{
    // [buf][ A: 256x32 (8192 us) | B: 256x32 (8192 us) ] = 32KB/buf, 128KB
    __shared__ ushort_t lds[4][16384];

    const int t = threadIdx.x;
    const int mBase = blockIdx.x * 256;
    const int nBase = blockIdx.y * 256;

    const int lane = t & 63;
    const int wv = t >> 6;
    const int wm = (wv >> 2) * 128;      // wave m-offset: 0 / 128
    const int wn = (wv & 3) * 64;        // wave n-offset: 0/64/128/192
    const int fr = lane & 15;
    const int fq = lane >> 4;
    const int fsw2 = (fq ^ ((fr >> 1) & 3)) * 16;   // swizzled chunk, BYTES

    // per-wave LDS byte bases (frag i/j at immediate offset i*1024 / j*1024)
    const unsigned aBase = (unsigned)((wm + fr) * 64 + fsw2);
    const unsigned bBase = (unsigned)(16384 + (wn + fr) * 64 + fsw2);

    // staging: thread t covers chunk (t&3) of row (t>>2), pre-swizzled src
    const int r0 = t >> 2;
    const int sc0 = ((t & 3) ^ ((r0 >> 1) & 3)) * 8;
    const size_t aRow0 = (size_t)(mBase + r0) * 1536 + sc0;
    const size_t aRow1 = (size_t)(mBase + r0 + 128) * 1536 + sc0;
    const size_t wRow0 = (size_t)(nBase + r0) * 1536 + sc0;
    const size_t wRow1 = (size_t)(nBase + r0 + 128) * 1536 + sc0;

    f32x4 acc[8][4];
#pragma unroll
    for (int i = 0; i < 8; i++)
#pragma unroll
        for (int j = 0; j < 4; j++) {
            f32x4 z = {0.f, 0.f, 0.f, 0.f};
            acc[i][j] = z;
        }

#define STG_A0(tile) gload16(&A[aRow0 + (size_t)(tile) * 32], &lds[(tile) & 3][t * 8])
#define STG_A1(tile) gload16(&A[aRow1 + (size_t)(tile) * 32], &lds[(tile) & 3][4096 + t * 8])
#define STG_B0(tile) gload16(&W[wRow0 + (size_t)(tile) * 32], &lds[(tile) & 3][8192 + t * 8])
#define STG_B1(tile) gload16(&W[wRow1 + (size_t)(tile) * 32], &lds[(tile) & 3][12288 + t * 8])

    // prologue: tiles 0,1 fully staged; t0 guaranteed landed for all waves
    STG_A0(0); STG_A1(0); STG_B0(0); STG_B1(0);
    STG_A0(1); STG_A1(1); STG_B0(1); STG_B1(1);
    asm volatile("s_waitcnt vmcnt(4)");
    __builtin_amdgcn_s_barrier();

    for (int tt = 0; tt < 48; ++tt) {
        const unsigned bufOff = (unsigned)((tt & 3) << 15);
        const unsigned av = aBase + bufOff;
        const unsigned bv = bBase + bufOff;
        bf16x8 af0, af1, af2, af3, wf0, wf1, wf2, wf3;

        // ---------------- phase A (ih = 0) ----------------
        DSREAD(af0, av, 0);
        DSREAD(af1, av, 1024);
        DSREAD(af2, av, 2048);
        DSREAD(af3, av, 3072);
        DSREAD(wf0, bv, 0);
        DSREAD(wf1, bv, 1024);
        DSREAD(wf2, bv, 2048);
        DSREAD(wf3, bv, 3072);
        if (tt < 46) { STG_A0(tt + 2); STG_A1(tt + 2); }
        __builtin_amdgcn_s_barrier();
        asm volatile("s_waitcnt lgkmcnt(0)");
        __builtin_amdgcn_sched_barrier(0);
        __builtin_amdgcn_s_setprio(1);
        MM(0, 0, af0, wf0); MM(0, 1, af0, wf1); MM(0, 2, af0, wf2); MM(0, 3, af0, wf3);
        MM(1, 0, af1, wf0); MM(1, 1, af1, wf1); MM(1, 2, af1, wf2); MM(1, 3, af1, wf3);
        MM(2, 0, af2, wf0); MM(2, 1, af2, wf1); MM(2, 2, af2, wf2); MM(2, 3, af2, wf3);
        MM(3, 0, af3, wf0); MM(3, 1, af3, wf1); MM(3, 2, af3, wf2); MM(3, 3, af3, wf3);
        __builtin_amdgcn_s_setprio(0);
        __builtin_amdgcn_s_barrier();

        // ---------------- phase B (ih = 1) ----------------
        DSREAD(af0, av, 4096);
        DSREAD(af1, av, 5120);
        DSREAD(af2, av, 6144);
        DSREAD(af3, av, 7168);
        if (tt < 46) { STG_B0(tt + 2); STG_B1(tt + 2); }
        // counted wait, once per K-tile, BEFORE the barrier -> collective
        if (tt < 46) {
            asm volatile("s_waitcnt vmcnt(4)");
        } else if (tt == 46) {
            asm volatile("s_waitcnt vmcnt(0)");
        }
        __builtin_amdgcn_s_barrier();
        asm volatile("s_waitcnt lgkmcnt(0)");
        __builtin_amdgcn_sched_barrier(0);
        __builtin_amdgcn_s_setprio(1);
        MM(4, 0, af0, wf0); MM(4, 1, af0, wf1); MM(4, 2, af0, wf2); MM(4, 3, af0, wf3);
        MM(5, 0, af1, wf0); MM(5, 1, af1, wf1); MM(5, 2, af1, wf2); MM(5, 3, af1, wf3);
        MM(6, 0, af2, wf0); MM(6, 1, af2, wf1); MM(6, 2, af2, wf2); MM(6, 3, af2, wf3);
        MM(7, 0, af3, wf0); MM(7, 1, af3, wf1); MM(7, 2, af3, wf2); MM(7, 3, af3, wf3);
        __builtin_amdgcn_s_setprio(0);
        __builtin_amdgcn_s_barrier();
    }
#undef STG_A0
#undef STG_A1
#undef STG_B0
#undef STG_B1

    // epilogue: C/D layout col=lane&15, row=(lane>>4)*4+reg
#pragma unroll
    for (int j = 0; j < 4; j++) {
        const int col = nBase + wn + j * 16 + fr;
        const float bv = bias[col];
#pragma unroll
        for (int i = 0; i < 8; i++)
#pragma unroll
            for (int r = 0; r < 4; r++) {
                const int row = mBase + wm + i * 16 + fq * 4 + r;
                C[(size_t)row * 3072 + col] = acc[i][j][r] + bv;
            }
    }
}

// ---------------------------------------------------------------------------
// MLP layer 1, int8 MFMA at FULL rate (16x16x64, 16B frags):
// A = spike counts 0..15 (exact in i8), W = per-row-quantized int8.
// 64x128 tile, 256 threads = 4 waves side-by-side in n (per-wave 64x32,
// acc[4][2]).  BK=64 bytes.  Chunk swizzle (16B chunks).
// Direct epilogue: fp32(acc)*wsc[col] + bias[col], relu, bf16.
// ---------------------------------------------------------------------------
__global__ __launch_bounds__(256) void mlp1_i8(
    const signed char* __restrict__ A, const signed char* __restrict__ W,
    const float* __restrict__ wsc, const float* __restrict__ bias,
    ushort_t* __restrict__ C)
{
    __shared__ signed char sA[64 * 64];    // 4 KB
    __shared__ signed char sW[128 * 64];   // 8 KB

    const int t = threadIdx.x;
    const int mBase = blockIdx.x * 64;
    const int nBase = blockIdx.y * 128;

    const int lane = t & 63;
    const int wv = t >> 6;
    const int wn = wv * 32;
    const int fr = lane & 15;
    const int fq = lane >> 4;            // k-offset = fq*16 bytes
    const int fsw = (fq ^ ((fr >> 1) & 3)) * 16;  // swizzled read chunk (bytes)

    const int r0 = t >> 2;                           // staging row 0..63
    const int cc = ((t & 3) ^ ((t >> 3) & 3)) * 16;  // pre-swizzled src byte-col

    i32x4 acc[4][2];
#pragma unroll
    for (int i = 0; i < 4; i++)
#pragma unroll
        for (int j = 0; j < 2; j++) {
            i32x4 z = {0, 0, 0, 0};
            acc[i][j] = z;
        }

    for (int k0 = 0; k0 < 4096; k0 += 64) {
        gload16(&A[(size_t)(mBase + r0) * 4096 + k0 + cc], &sA[t * 16]);
        gload16(&W[(size_t)(nBase + r0) * 4096 + k0 + cc], &sW[t * 16]);
        gload16(&W[(size_t)(nBase + 64 + r0) * 4096 + k0 + cc], &sW[4096 + t * 16]);
        __syncthreads();

        i32x4 af[4], wf[2];
#pragma unroll
        for (int i = 0; i < 4; i++)
            af[i] = *(const i32x4*)&sA[(i * 16 + fr) * 64 + fsw];
#pragma unroll
        for (int j = 0; j < 2; j++)
            wf[j] = *(const i32x4*)&sW[(wn + j * 16 + fr) * 64 + fsw];
#pragma unroll
        for (int i = 0; i < 4; i++)
#pragma unroll
            for (int j = 0; j < 2; j++)
                acc[i][j] = __builtin_amdgcn_mfma_i32_16x16x64_i8(af[i], wf[j], acc[i][j], 0, 0, 0);
        __syncthreads();
    }

#pragma unroll
    for (int j = 0; j < 2; j++) {
        const int col = nBase + wn + j * 16 + fr;
        const float sc = wsc[col];
        const float bv = bias[col];
#pragma unroll
        for (int i = 0; i < 4; i++)
#pragma unroll
            for (int r = 0; r < 4; r++) {
                const int row = mBase + i * 16 + fq * 4 + r;
                const float v = (float)acc[i][j][r] * sc + bv;
                C[(size_t)row * 2048 + col] = f2bf(fmaxf(v, 0.f));
            }
    }
}

// ---------------------------------------------------------------------------
// MLP layer 2: bf16, 64x128 tile, 4 waves side-by-side in n (per-wave 64x32),
// BK=32, grid 32x16 = 512 blocks, direct epilogue (bias+relu+bf16).
// Block-diagonal: upper n-half reads A columns at +aHalfOff.
// ---------------------------------------------------------------------------
__global__ __launch_bounds__(256) void mlp2_bf16(
    const ushort_t* __restrict__ A, const ushort_t* __restrict__ W,
    const float* __restrict__ bias, ushort_t* __restrict__ C,
    int N, int K, int lda, int ldw, int ldc, int aHalfOff)
{
    __shared__ ushort_t sA[64 * 32];
    __shared__ ushort_t sW[128 * 32];

    const int t = threadIdx.x;
    const int mBase = blockIdx.x * 64;
    const int nBase = blockIdx.y * 128;
    const int aOff = (2 * nBase >= N) ? aHalfOff : 0;

    const int lane = t & 63;
    const int wv = t >> 6;
    const int wn = wv * 32;
    const int fr = lane & 15;
    const int fq = lane >> 4;
    const int fsw = (fq ^ ((fr >> 1) & 3)) * 8;   // swizzled read chunk (ushorts)

    const int r0 = t >> 2;                           // 0..63
    const int cc = ((t & 3) ^ ((t >> 3) & 3)) * 8;   // pre-swizzled src k-col

    f32x4 acc[4][2];
#pragma unroll
    for (int i = 0; i < 4; i++)
#pragma unroll
        for (int j = 0; j < 2; j++) {
            f32x4 z = {0.f, 0.f, 0.f, 0.f};
            acc[i][j] = z;
        }

    for (int k0 = 0; k0 < K; k0 += 32) {
        gload16(&A[(size_t)(mBase + r0) * lda + aOff + k0 + cc], &sA[t * 8]);
        gload16(&W[(size_t)(nBase + r0) * ldw + k0 + cc], &sW[t * 8]);
        gload16(&W[(size_t)(nBase + 64 + r0) * ldw + k0 + cc], &sW[2048 + t * 8]);
        __syncthreads();

        bf16x8 af[4], wf[2];
#pragma unroll
        for (int i = 0; i < 4; i++)
            af[i] = *(const bf16x8*)&sA[(i * 16 + fr) * 32 + fsw];
#pragma unroll
        for (int j = 0; j < 2; j++)
            wf[j] = *(const bf16x8*)&sW[(wn + j * 16 + fr) * 32 + fsw];
#pragma unroll
        for (int i = 0; i < 4; i++)
#pragma unroll
            for (int j = 0; j < 2; j++)
                acc[i][j] = __builtin_amdgcn_mfma_f32_16x16x32_bf16(af[i], wf[j], acc[i][j], 0, 0, 0);
        __syncthreads();
    }

#pragma unroll
    for (int j = 0; j < 2; j++) {
        const int col = nBase + wn + j * 16 + fr;
        const float bv = bias[col];
#pragma unroll
        for (int i = 0; i < 4; i++)
#pragma unroll
            for (int r = 0; r < 4; r++) {
                const int row = mBase + i * 16 + fq * 4 + r;
                C[(size_t)row * ldc + col] = f2bf(fmaxf(acc[i][j][r] + bv, 0.f));
            }
    }
}

// ---------------------------------------------------------------------------
// LIF recurrence over 15 steps; cur: [B*5, 3072] fp32 (i1|i2|i3 per channel),
// writes spike COUNTS (0..15) as int8 to x [2048, 4096] (col = c*4 + j).
// ---------------------------------------------------------------------------
__global__ __launch_bounds__(256) void recur_kernel(
    const float* __restrict__ cur, const float* __restrict__ wl,
    const float* __restrict__ bl, signed char* __restrict__ x)
{
    const int idx = blockIdx.x * 256 + threadIdx.x;
    const int b = idx >> 10, c = idx & 1023;
    const float wl0 = wl[0], wl1 = wl[1], wl2 = wl[2], bl0 = bl[0];
    float m0 = 0, m1 = 0, m2 = 0, m3 = 0;
    int s0 = 0, s1 = 0, s2 = 0, s3 = 0;
#pragma unroll
    for (int f = 0; f < 5; f++) {
        const float* p = cur + (size_t)(b * 5 + f) * 3072 + c;
        const float i1 = p[0], i2 = p[1024], i3 = p[2048];
#pragma unroll
        for (int rep = 0; rep < 3; rep++) {
            const float inner = m0 * wl0 + m1 * wl1 + m2 * wl2 + bl0;
            const float n0 = i1 + ((m0 > THRESH) ? 0.f : DECAY * m0);
            const float n1 = i2 + ((m1 > THRESH) ? 0.f : DECAY * m1);
            const float n2 = i3 + ((m2 > THRESH) ? 0.f : DECAY * m2);
            const float n3 = inner + ((m3 > THRESH) ? 0.f : DECAY * m3);
            m0 = n0; m1 = n1; m2 = n2; m3 = n3;
            s0 += (n0 > THRESH); s1 += (n1 > THRESH);
            s2 += (n2 > THRESH); s3 += (n3 > THRESH);
        }
    }
    uchar4 o;
    o.x = (unsigned char)s0; o.y = (unsigned char)s1;
    o.z = (unsigned char)s2; o.w = (unsigned char)s3;
    *(uchar4*)&x[(size_t)b * 4096 + c * 4] = o;
}

// ---------------------------------------------------------------------------
// Consolidated prep:
//  - state -> A' = [hi | hi | lo]   (rows 10240, K' = 1536)
//  - w1/w2/w3 -> W' = [hi | lo | hi] (rows 3072, K' = 1536)
//  - w11|w21 -> int8 rows with per-row scale (wsc[n] = rowmax/127/15)
//  - w12/w22 -> bf16
//  - bias packing
// ---------------------------------------------------------------------------
__device__ __forceinline__ void split_state(const float4* src, ushort4* dst,
                                            int base, int t) {
#pragma unroll
    for (int p = 0; p < 4; p++) {
        const int i = base * 1024 + p * 256 + t;
        const float4 v = src[i];
        ushort4 h, l;
        h.x = f2bf(v.x); l.x = f2bf(v.x - bf2f(h.x));
        h.y = f2bf(v.y); l.y = f2bf(v.y - bf2f(h.y));
        h.z = f2bf(v.z); l.z = f2bf(v.z - bf2f(h.z));
        h.w = f2bf(v.w); l.w = f2bf(v.w - bf2f(h.w));
        const int r = i >> 7, c = i & 127;       // row (512-float rows), float4 col
        ushort4* row = dst + (size_t)r * 384;    // 1536 ushorts = 384 ushort4
        row[c] = h; row[128 + c] = h; row[256 + c] = l;   // [hi | hi | lo]
    }
}
__device__ __forceinline__ void split_w(const float4* src, ushort4* dst,
                                        int base, int t, int roff) {
#pragma unroll
    for (int p = 0; p < 4; p++) {
        const int i = base * 1024 + p * 256 + t;
        const float4 v = src[i];
        ushort4 h, l;
        h.x = f2bf(v.x); l.x = f2bf(v.x - bf2f(h.x));
        h.y = f2bf(v.y); l.y = f2bf(v.y - bf2f(h.y));
        h.z = f2bf(v.z); l.z = f2bf(v.z - bf2f(h.z));
        h.w = f2bf(v.w); l.w = f2bf(v.w - bf2f(h.w));
        const int r = (i >> 7) + roff, c = i & 127;
        ushort4* row = dst + (size_t)r * 384;
        row[c] = h; row[128 + c] = l; row[256 + c] = h;   // [hi | lo | hi]
    }
}
__device__ __forceinline__ void do_cvt4(const float4* src, ushort4* dst,
                                        int base, int t) {
#pragma unroll
    for (int p = 0; p < 4; p++) {
        const int i = base * 1024 + p * 256 + t;
        const float4 v = src[i];
        ushort4 h;
        h.x = f2bf(v.x); h.y = f2bf(v.y); h.z = f2bf(v.z); h.w = f2bf(v.w);
        dst[i] = h;
    }
}
__device__ __forceinline__ int q8(float x, float inv) {
    int q = (int)rintf(x * inv);
    q = q > 127 ? 127 : (q < -127 ? -127 : q);
    return q & 0xff;
}

__global__ __launch_bounds__(256) void prep_kernel(
    const float* __restrict__ state,
    const float* __restrict__ w1, const float* __restrict__ w2,
    const float* __restrict__ w3,
    const float* __restrict__ w11, const float* __restrict__ w21,
    const float* __restrict__ w12, const float* __restrict__ w22,
    const float* __restrict__ b1, const float* __restrict__ b2,
    const float* __restrict__ b3, const float* __restrict__ b11,
    const float* __restrict__ b21, const float* __restrict__ b12,
    const float* __restrict__ b22,
    ushort_t* __restrict__ Ap, ushort_t* __restrict__ Wp,
    signed char* __restrict__ w1q, float* __restrict__ wsc,
    ushort_t* __restrict__ w2b,
    float* __restrict__ b123, float* __restrict__ bb1, float* __restrict__ bb2)
{
    const int bid = blockIdx.x;
    const int t = threadIdx.x;
    if (bid < 1280) {
        split_state((const float4*)state, (ushort4*)Ap, bid, t);
    } else if (bid < 1408) {
        split_w((const float4*)w1, (ushort4*)Wp, bid - 1280, t, 0);
    } else if (bid < 1536) {
        split_w((const float4*)w2, (ushort4*)Wp, bid - 1408, t, 1024);
    } else if (bid < 1664) {
        split_w((const float4*)w3, (ushort4*)Wp, bid - 1536, t, 2048);
    } else if (bid < 3712) {
        // one block per output row of [w11 ; w21] -> int8 + per-row scale
        const int r = bid - 1664;
        const float* src = (r < 1024) ? (w11 + (size_t)r * 4096)
                                      : (w21 + (size_t)(r - 1024) * 4096);
        __shared__ float red[256];
        float4 v[4];
        float lmax = 0.f;
#pragma unroll
        for (int p = 0; p < 4; p++) {
            v[p] = ((const float4*)src)[t * 4 + p];
            lmax = fmaxf(lmax, fmaxf(fmaxf(fabsf(v[p].x), fabsf(v[p].y)),
                                     fmaxf(fabsf(v[p].z), fabsf(v[p].w))));
        }
        red[t] = lmax;
        __syncthreads();
        for (int s = 128; s > 0; s >>= 1) {
            if (t < s) red[t] = fmaxf(red[t], red[t + s]);
            __syncthreads();
        }
        const float gmax = fmaxf(red[0], 1e-30f);
        const float inv = 127.0f / gmax;
        int4 o;
        o.x = q8(v[0].x, inv) | (q8(v[0].y, inv) << 8) | (q8(v[0].z, inv) << 16) | (q8(v[0].w, inv) << 24);
        o.y = q8(v[1].x, inv) | (q8(v[1].y, inv) << 8) | (q8(v[1].z, inv) << 16) | (q8(v[1].w, inv) << 24);
        o.z = q8(v[2].x, inv) | (q8(v[2].y, inv) << 8) | (q8(v[2].z, inv) << 16) | (q8(v[2].w, inv) << 24);
        o.w = q8(v[3].x, inv) | (q8(v[3].y, inv) << 8) | (q8(v[3].z, inv) << 16) | (q8(v[3].w, inv) << 24);
        ((int4*)(w1q + (size_t)r * 4096))[t] = o;
        if (t == 0) wsc[r] = gmax / (127.0f * 15.0f);
    } else if (bid < 3968) {
        do_cvt4((const float4*)w12, (ushort4*)w2b, bid - 3712, t);
    } else if (bid < 4224) {
        do_cvt4((const float4*)w22, (ushort4*)(w2b + 1048576), bid - 3968, t);
    } else {
#pragma unroll
        for (int p = 0; p < 4; p++) {
            const int i = p * 256 + t;
            b123[i] = b1[i]; b123[1024 + i] = b2[i]; b123[2048 + i] = b3[i];
            bb1[i] = b11[i]; bb1[1024 + i] = b21[i];
            bb2[i] = b12[i]; bb2[1024 + i] = b22[i];
        }
    }
}

// ---------------------------------------------------------------------------
// Heads (both branches): out[b][n] = (clip?)(h2[b][off+k] . w[n][k] + bias[n])
// ---------------------------------------------------------------------------
__global__ __launch_bounds__(256) void head_kernel(
    const ushort_t* __restrict__ h, const float* __restrict__ wm,
    const float* __restrict__ bm, const float* __restrict__ ws,
    const float* __restrict__ bs, float* __restrict__ out)
{
    const int t = threadIdx.x;
    const int branch = blockIdx.x >> 8;
    const int n = t & 31;
    const int b = (blockIdx.x & 255) * 8 + (t >> 5);
    const ushort_t* hr = h + (size_t)b * 2048 + branch * 1024;
    const float* wr = (branch ? ws : wm) + (size_t)n * 1024;
    float s = 0.f;
#pragma unroll 4
    for (int k = 0; k < 1024; k += 8) {
        const uint4 hv = *(const uint4*)&hr[k];
        const float4 w0 = *(const float4*)&wr[k];
        const float4 w1 = *(const float4*)&wr[k + 4];
        s += blo(hv.x) * w0.x + bhi(hv.x) * w0.y
           + blo(hv.y) * w0.z + bhi(hv.y) * w0.w
           + blo(hv.z) * w1.x + bhi(hv.z) * w1.y
           + blo(hv.w) * w1.z + bhi(hv.w) * w1.w;
    }
    s += (branch ? bs : bm)[n];
    if (branch) s = fminf(fmaxf(s, -20.f), 2.f);
    out[(size_t)branch * 65536 + (size_t)b * 32 + n] = s;
}

// ---------------------------------------------------------------------------
extern "C" void kernel_launch(void* const* d_in, const int* in_sizes, int n_in,
                              void* d_out, int out_size, void* d_ws, size_t ws_size,
                              hipStream_t stream)
{
    const float* state = (const float*)d_in[0];
    const float* w1  = (const float*)d_in[1];  const float* b1  = (const float*)d_in[2];
    const float* w2  = (const float*)d_in[3];  const float* b2  = (const float*)d_in[4];
    const float* w3  = (const float*)d_in[5];  const float* b3  = (const float*)d_in[6];
    const float* wl  = (const float*)d_in[7];  const float* bl  = (const float*)d_in[8];
    const float* w11 = (const float*)d_in[9];  const float* b11 = (const float*)d_in[10];
    const float* w12 = (const float*)d_in[11]; const float* b12 = (const float*)d_in[12];
    const float* w21 = (const float*)d_in[13]; const float* b21 = (const float*)d_in[14];
    const float* w22 = (const float*)d_in[15]; const float* b22 = (const float*)d_in[16];
    const float* wm  = (const float*)d_in[17]; const float* bm  = (const float*)d_in[18];
    const float* ws  = (const float*)d_in[19]; const float* bs  = (const float*)d_in[20];
    float* out = (float*)d_out;

    // ---- workspace layout ----
    char* wp = (char*)d_ws;
    float*       cur   = (float*)wp;       wp += (size_t)10240 * 3072 * 4;   // 126MB
    ushort_t*    Ap    = (ushort_t*)wp;    wp += (size_t)10240 * 1536 * 2;   // 31.5MB
    ushort_t*    Wp    = (ushort_t*)wp;    wp += (size_t)3072 * 1536 * 2;    // 9.4MB
    signed char* xb    = (signed char*)wp; wp += (size_t)2048 * 4096;        // int8 counts
    signed char* w1q   = (signed char*)wp; wp += (size_t)2048 * 4096;        // int8 [w11;w21]
    ushort_t*    w2b   = (ushort_t*)wp;    wp += (size_t)2048 * 1024 * 2;
    ushort_t*    h1    = (ushort_t*)wp;    wp += (size_t)2048 * 2048 * 2;
    ushort_t*    h2    = (ushort_t*)wp;    wp += (size_t)2048 * 2048 * 2;
    float*       wsc   = (float*)wp;       wp += 2048 * 4;
    float*       b123  = (float*)wp;       wp += 3072 * 4;
    float*       bb1   = (float*)wp;       wp += 2048 * 4;
    float*       bb2   = (float*)wp;       wp += 2048 * 4;

    // ---- prep: splits (concat-K layouts), int8 quant, cvts, bias packing ----
    prep_kernel<<<4225, 256, 0, stream>>>(
        state, w1, w2, w3, w11, w21, w12, w22,
        b1, b2, b3, b11, b21, b12, b22,
        Ap, Wp, w1q, wsc, w2b, b123, bb1, bb2);

    // ---- currents GEMM: [10240,1536] x [3072,1536]^T -> cur (fp32+bias) ----
    cur_gemm_8ph<<<dim3(40, 12), 512, 0, stream>>>(Ap, Wp, b123, cur);

    // ---- recurrence -> spike counts int8 [2048, 4096] ----
    recur_kernel<<<8192, 256, 0, stream>>>(cur, wl, bl, xb);

    // ---- MLP layer 1 (both branches) i8 K=64 MFMA, 512 blocks ----
    mlp1_i8<<<dim3(32, 16), 256, 0, stream>>>(xb, w1q, wsc, bb1, h1);

    // ---- MLP layer 2 (block-diagonal) bf16, 512 blocks ----
    mlp2_bf16<<<dim3(32, 16), 256, 0, stream>>>(
        h1, w2b, bb2, h2, 2048, 1024, 2048, 1024, 2048, 1024);

    // ---- heads (both branches) ----
    head_kernel<<<512, 256, 0, stream>>>(h2, wm, bm, ws, bs, out);
}

// Round 4
// 370.090 us; speedup vs baseline: 1.0443x; 1.0443x over previous
//
#include <hip/hip_runtime.h>
#include <cstddef>
#include <cstdint>

#define THRESH 0.8f
#define DECAY  0.2f

typedef unsigned short ushort_t;
typedef __attribute__((ext_vector_type(8))) short bf16x8;
typedef __attribute__((ext_vector_type(4))) float f32x4;
typedef __attribute__((ext_vector_type(4))) int i32x4;   // also 16 x i8 operand

__device__ __forceinline__ ushort_t f2bf(float f) {
    union { float f; unsigned u; } v; v.f = f;
    unsigned r = v.u + 0x7FFFu + ((v.u >> 16) & 1u);
    return (ushort_t)(r >> 16);
}
__device__ __forceinline__ float bf2f(ushort_t h) {
    union { unsigned u; float f; } v; v.u = ((unsigned)h) << 16;
    return v.f;
}
__device__ __forceinline__ float blo(unsigned u) {
    union { unsigned x; float f; } v; v.x = u << 16; return v.f;
}
__device__ __forceinline__ float bhi(unsigned u) {
    union { unsigned x; float f; } v; v.x = u & 0xFFFF0000u; return v.f;
}

// async global->LDS, 16B per lane; LDS dest = wave-uniform base + lane*16
__device__ __forceinline__ void gload16(const void* g, void* l) {
    __builtin_amdgcn_global_load_lds(
        (const __attribute__((address_space(1))) void*)g,
        (__attribute__((address_space(3))) void*)l,
        16, 0, 0);
}

// compiler-invisible LDS read (keeps waitcnt control out of the compiler)
#define DSREAD(dst, addr, off) \
    asm volatile("ds_read_b128 %0, %1 offset:" #off : "=v"(dst) : "v"(addr))

#define MM(i, j, a, w) \
    acc[i][j] = __builtin_amdgcn_mfma_f32_16x16x32_bf16(a, w, acc[i][j], 0, 0, 0)

// ---------------------------------------------------------------------------
// Fused currents-GEMM + LIF recurrence.
//   A'' = row-permuted [Ah|Ah|Al] (10240 x 1536): row m <- state row (b,f),
//         b = (m/160)*32 + ((m%160)/80)*16 + (m%16),  f = (m%80)/16
//   W'' = row-permuted [Wh|Wl|Wh] (3072 x 1536): row n <- w_j[c],
//         j = (n%48)/16,  c = (n/192)*64 + ((n%192)/48)*16 + (n%16)
// Tile 160x192, 8 waves (2m x 4n), per-wave 80x48 = acc[5][3].  With the
// permutations, lane (fq,fr) of a wave ends up holding, for 4 batches
// (r=0..3) x 1 channel, all 15 currents (5 frames x i1/i2/i3) -> the LIF
// recurrence runs fully in-register in the epilogue and writes spike
// counts directly (cur + recur_kernel eliminated: -252 MB HBM traffic).
// Pipeline: 3 LDS buffers (67.5 KB -> 2 blocks/CU), prefetch distance 2,
// wave-role staging (waves 0-4: A, 5-7: B), per-wave counted vmcnt
// (4/8 steady state, never 0 in-loop), asm ds_reads, 2 barriers/tile,
// setprio around the MFMA cluster.  Chunk swizzle as proven in R1
// (bank conflicts == 0).
// ---------------------------------------------------------------------------
__global__ __launch_bounds__(512, 4) void fused_cur_lif(
    const ushort_t* __restrict__ A, const ushort_t* __restrict__ W,
    const float* __restrict__ b123, const float* __restrict__ wl,
    const float* __restrict__ bl, signed char* __restrict__ xb)
{
    // [buf][ A: 160x32 (5120 us) | B: 192x32 (6144 us) ] = 22.5KB x 3
    __shared__ ushort_t lds[3][11264];

    const int t = threadIdx.x;
    const int bx = blockIdx.x;           // 0..63  (m: 32 batches each)
    const int by = blockIdx.y;           // 0..15  (n: 64 channels each)
    const int lane = t & 63;
    const int wv = t >> 6;
    const int wm = (wv >> 2) * 80;       // wave m-offset: 0 / 80
    const int wn = (wv & 3) * 48;        // wave n-offset: 0/48/96/144
    const int fr = lane & 15;
    const int fq = lane >> 4;
    const int swz16 = (fq ^ ((fr >> 1) & 3)) * 16;   // read swizzle, bytes

    // LDS byte bases for fragment reads (A at 0, B at 10240 bytes)
    const unsigned a0 = (unsigned)((wm + fr) * 64 + swz16);
    const unsigned b0 = (unsigned)(10240 + (wn + fr) * 64 + swz16);

    // staging role: waves 0-4 stage A (2 x 16-row groups), 5-7 stage B (4)
    const ushort_t* src0; const ushort_t* src1;
    const ushort_t* src2; const ushort_t* src3;
    int dst0, dst1, dst2, dst3;
    if (wv < 5) {
        const int rl0 = wv * 32 + (lane >> 2);
        const int rl1 = rl0 + 16;
        src0 = A + (size_t)(bx * 160 + rl0) * 1536 + ((lane & 3) ^ ((rl0 >> 1) & 3)) * 8;
        src1 = A + (size_t)(bx * 160 + rl1) * 1536 + ((lane & 3) ^ ((rl1 >> 1) & 3)) * 8;
        src2 = src0; src3 = src1;
        dst0 = rl0 * 32 + (lane & 3) * 8;
        dst1 = rl1 * 32 + (lane & 3) * 8;
        dst2 = dst0; dst3 = dst1;
    } else {
        const int rb = (wv - 5) * 64 + (lane >> 2);
        src0 = W + (size_t)(by * 192 + rb) * 1536 + ((lane & 3) ^ ((rb >> 1) & 3)) * 8;
        src1 = src0 + (size_t)16 * 1536;
        src2 = src0 + (size_t)32 * 1536;
        src3 = src0 + (size_t)48 * 1536;
        dst0 = 5120 + rb * 32 + (lane & 3) * 8;
        dst1 = dst0 + 16 * 32;
        dst2 = dst0 + 32 * 32;
        dst3 = dst0 + 48 * 32;
    }

#define STAGE(tile, sbuf)                                              \
    do {                                                               \
        const int k0_ = (tile) * 32;                                   \
        ushort_t* lb_ = &lds[sbuf][0];                                 \
        if (wv < 5) {                                                  \
            gload16(src0 + k0_, lb_ + dst0);                           \
            gload16(src1 + k0_, lb_ + dst1);                           \
        } else {                                                       \
            gload16(src0 + k0_, lb_ + dst0);                           \
            gload16(src1 + k0_, lb_ + dst1);                           \
            gload16(src2 + k0_, lb_ + dst2);                           \
            gload16(src3 + k0_, lb_ + dst3);                           \
        }                                                              \
    } while (0)

    f32x4 acc[5][3];
#pragma unroll
    for (int i = 0; i < 5; i++)
#pragma unroll
        for (int j = 0; j < 3; j++) {
            f32x4 z = {0.f, 0.f, 0.f, 0.f};
            acc[i][j] = z;
        }

    // prologue: tiles 0,1 in flight
    STAGE(0, 0);
    STAGE(1, 1);

    int cb = 0, sb = 2;
    for (int tt = 0; tt < 48; ++tt) {
        if (tt < 46) STAGE(tt + 2, sb);
        // per-wave counted vmcnt: wait only the OLDEST tile's loads
        if (wv < 5) {
            if (tt < 46)       asm volatile("s_waitcnt vmcnt(4)" ::: "memory");
            else if (tt == 46) asm volatile("s_waitcnt vmcnt(2)" ::: "memory");
            else               asm volatile("s_waitcnt vmcnt(0)" ::: "memory");
        } else {
            if (tt < 46)       asm volatile("s_waitcnt vmcnt(8)" ::: "memory");
            else if (tt == 46) asm volatile("s_waitcnt vmcnt(4)" ::: "memory");
            else               asm volatile("s_waitcnt vmcnt(0)" ::: "memory");
        }
        __builtin_amdgcn_s_barrier();
        __builtin_amdgcn_sched_barrier(0);

        const unsigned av = (unsigned)(cb * 22528) + a0;
        const unsigned bv = (unsigned)(cb * 22528) + b0;
        bf16x8 af0, af1, af2, af3, af4, wf0, wf1, wf2;
        DSREAD(af0, av, 0);
        DSREAD(af1, av, 1024);
        DSREAD(af2, av, 2048);
        DSREAD(af3, av, 3072);
        DSREAD(af4, av, 4096);
        DSREAD(wf0, bv, 0);
        DSREAD(wf1, bv, 1024);
        DSREAD(wf2, bv, 2048);
        asm volatile("s_waitcnt lgkmcnt(0)" ::: "memory");
        __builtin_amdgcn_sched_barrier(0);
        __builtin_amdgcn_s_setprio(1);
        MM(0, 0, af0, wf0); MM(0, 1, af0, wf1); MM(0, 2, af0, wf2);
        MM(1, 0, af1, wf0); MM(1, 1, af1, wf1); MM(1, 2, af1, wf2);
        MM(2, 0, af2, wf0); MM(2, 1, af2, wf1); MM(2, 2, af2, wf2);
        MM(3, 0, af3, wf0); MM(3, 1, af3, wf1); MM(3, 2, af3, wf2);
        MM(4, 0, af4, wf0); MM(4, 1, af4, wf1); MM(4, 2, af4, wf2);
        __builtin_amdgcn_s_setprio(0);
        __builtin_amdgcn_s_barrier();     // release buffer cb for re-staging
        __builtin_amdgcn_sched_barrier(0);

        cb = (cb == 2) ? 0 : cb + 1;
        sb = (sb == 2) ? 0 : sb + 1;
    }
#undef STAGE

    // ---- epilogue: in-register LIF recurrence (replaces recur_kernel) ----
    // lane holds: batches bbase+r (r=0..3), channel ch; acc[f][j][r] = the
    // current of matrix j (w1/w2/w3), frame f, batch r.
    const int ch = by * 64 + (wv & 3) * 16 + fr;
    const float b1c = b123[ch];
    const float b2c = b123[1024 + ch];
    const float b3c = b123[2048 + ch];
    const float wl0 = wl[0], wl1 = wl[1], wl2 = wl[2], bl0 = bl[0];
    const int bbase = bx * 32 + (wv >> 2) * 16 + fq * 4;
#pragma unroll
    for (int r = 0; r < 4; r++) {
        float m0 = 0.f, m1 = 0.f, m2 = 0.f, m3 = 0.f;
        int s0 = 0, s1 = 0, s2 = 0, s3 = 0;
#pragma unroll
        for (int f = 0; f < 5; f++) {
            const float i1 = acc[f][0][r] + b1c;
            const float i2 = acc[f][1][r] + b2c;
            const float i3 = acc[f][2][r] + b3c;
#pragma unroll
            for (int rep = 0; rep < 3; rep++) {
                const float inner = m0 * wl0 + m1 * wl1 + m2 * wl2 + bl0;
                const float n0 = i1 + ((m0 > THRESH) ? 0.f : DECAY * m0);
                const float n1 = i2 + ((m1 > THRESH) ? 0.f : DECAY * m1);
                const float n2 = i3 + ((m2 > THRESH) ? 0.f : DECAY * m2);
                const float n3 = inner + ((m3 > THRESH) ? 0.f : DECAY * m3);
                m0 = n0; m1 = n1; m2 = n2; m3 = n3;
                s0 += (n0 > THRESH); s1 += (n1 > THRESH);
                s2 += (n2 > THRESH); s3 += (n3 > THRESH);
            }
        }
        uchar4 o;
        o.x = (unsigned char)s0; o.y = (unsigned char)s1;
        o.z = (unsigned char)s2; o.w = (unsigned char)s3;
        *(uchar4*)&xb[(size_t)(bbase + r) * 4096 + ch * 4] = o;
    }
}

// ---------------------------------------------------------------------------
// MLP layer 1, int8 MFMA at FULL rate (16x16x64, 16B frags):
// A = spike counts 0..15 (exact in i8), W = per-row-quantized int8.
// 64x128 tile, 256 threads = 4 waves side-by-side in n (per-wave 64x32,
// acc[4][2]).  BK=64 bytes.  Chunk swizzle (16B chunks).
// Direct epilogue: fp32(acc)*wsc[col] + bias[col], relu, bf16.
// ---------------------------------------------------------------------------
__global__ __launch_bounds__(256) void mlp1_i8(
    const signed char* __restrict__ A, const signed char* __restrict__ W,
    const float* __restrict__ wsc, const float* __restrict__ bias,
    ushort_t* __restrict__ C)
{
    __shared__ signed char sA[64 * 64];    // 4 KB
    __shared__ signed char sW[128 * 64];   // 8 KB

    const int t = threadIdx.x;
    const int mBase = blockIdx.x * 64;
    const int nBase = blockIdx.y * 128;

    const int lane = t & 63;
    const int wv = t >> 6;
    const int wn = wv * 32;
    const int fr = lane & 15;
    const int fq = lane >> 4;            // k-offset = fq*16 bytes
    const int fsw = (fq ^ ((fr >> 1) & 3)) * 16;  // swizzled read chunk (bytes)

    const int r0 = t >> 2;                           // staging row 0..63
    const int cc = ((t & 3) ^ ((t >> 3) & 3)) * 16;  // pre-swizzled src byte-col

    i32x4 acc[4][2];
#pragma unroll
    for (int i = 0; i < 4; i++)
#pragma unroll
        for (int j = 0; j < 2; j++) {
            i32x4 z = {0, 0, 0, 0};
            acc[i][j] = z;
        }

    for (int k0 = 0; k0 < 4096; k0 += 64) {
        gload16(&A[(size_t)(mBase + r0) * 4096 + k0 + cc], &sA[t * 16]);
        gload16(&W[(size_t)(nBase + r0) * 4096 + k0 + cc], &sW[t * 16]);
        gload16(&W[(size_t)(nBase + 64 + r0) * 4096 + k0 + cc], &sW[4096 + t * 16]);
        __syncthreads();

        i32x4 af[4], wf[2];
#pragma unroll
        for (int i = 0; i < 4; i++)
            af[i] = *(const i32x4*)&sA[(i * 16 + fr) * 64 + fsw];
#pragma unroll
        for (int j = 0; j < 2; j++)
            wf[j] = *(const i32x4*)&sW[(wn + j * 16 + fr) * 64 + fsw];
#pragma unroll
        for (int i = 0; i < 4; i++)
#pragma unroll
            for (int j = 0; j < 2; j++)
                acc[i][j] = __builtin_amdgcn_mfma_i32_16x16x64_i8(af[i], wf[j], acc[i][j], 0, 0, 0);
        __syncthreads();
    }

#pragma unroll
    for (int j = 0; j < 2; j++) {
        const int col = nBase + wn + j * 16 + fr;
        const float sc = wsc[col];
        const float bv = bias[col];
#pragma unroll
        for (int i = 0; i < 4; i++)
#pragma unroll
            for (int r = 0; r < 4; r++) {
                const int row = mBase + i * 16 + fq * 4 + r;
                const float v = (float)acc[i][j][r] * sc + bv;
                C[(size_t)row * 2048 + col] = f2bf(fmaxf(v, 0.f));
            }
    }
}

// ---------------------------------------------------------------------------
// MLP layer 2: bf16, 64x128 tile, 4 waves side-by-side in n (per-wave 64x32),
// BK=32, grid 32x16 = 512 blocks, direct epilogue (bias+relu+bf16).
// Block-diagonal: upper n-half reads A columns at +aHalfOff.
// ---------------------------------------------------------------------------
__global__ __launch_bounds__(256) void mlp2_bf16(
    const ushort_t* __restrict__ A, const ushort_t* __restrict__ W,
    const float* __restrict__ bias, ushort_t* __restrict__ C,
    int N, int K, int lda, int ldw, int ldc, int aHalfOff)
{
    __shared__ ushort_t sA[64 * 32];
    __shared__ ushort_t sW[128 * 32];

    const int t = threadIdx.x;
    const int mBase = blockIdx.x * 64;
    const int nBase = blockIdx.y * 128;
    const int aOff = (2 * nBase >= N) ? aHalfOff : 0;

    const int lane = t & 63;
    const int wv = t >> 6;
    const int wn = wv * 32;
    const int fr = lane & 15;
    const int fq = lane >> 4;
    const int fsw = (fq ^ ((fr >> 1) & 3)) * 8;   // swizzled read chunk (ushorts)

    const int r0 = t >> 2;                           // 0..63
    const int cc = ((t & 3) ^ ((t >> 3) & 3)) * 8;   // pre-swizzled src k-col

    f32x4 acc[4][2];
#pragma unroll
    for (int i = 0; i < 4; i++)
#pragma unroll
        for (int j = 0; j < 2; j++) {
            f32x4 z = {0.f, 0.f, 0.f, 0.f};
            acc[i][j] = z;
        }

    for (int k0 = 0; k0 < K; k0 += 32) {
        gload16(&A[(size_t)(mBase + r0) * lda + aOff + k0 + cc], &sA[t * 8]);
        gload16(&W[(size_t)(nBase + r0) * ldw + k0 + cc], &sW[t * 8]);
        gload16(&W[(size_t)(nBase + 64 + r0) * ldw + k0 + cc], &sW[2048 + t * 8]);
        __syncthreads();

        bf16x8 af[4], wf[2];
#pragma unroll
        for (int i = 0; i < 4; i++)
            af[i] = *(const bf16x8*)&sA[(i * 16 + fr) * 32 + fsw];
#pragma unroll
        for (int j = 0; j < 2; j++)
            wf[j] = *(const bf16x8*)&sW[(wn + j * 16 + fr) * 32 + fsw];
#pragma unroll
        for (int i = 0; i < 4; i++)
#pragma unroll
            for (int j = 0; j < 2; j++)
                acc[i][j] = __builtin_amdgcn_mfma_f32_16x16x32_bf16(af[i], wf[j], acc[i][j], 0, 0, 0);
        __syncthreads();
    }

#pragma unroll
    for (int j = 0; j < 2; j++) {
        const int col = nBase + wn + j * 16 + fr;
        const float bv = bias[col];
#pragma unroll
        for (int i = 0; i < 4; i++)
#pragma unroll
            for (int r = 0; r < 4; r++) {
                const int row = mBase + i * 16 + fq * 4 + r;
                C[(size_t)row * ldc + col] = f2bf(fmaxf(acc[i][j][r] + bv, 0.f));
            }
    }
}

// ---------------------------------------------------------------------------
// Consolidated prep:
//  - state -> A'' (row-permuted, K-concat [hi|hi|lo])
//  - w1/w2/w3 -> W'' (row-permuted, K-concat [hi|lo|hi])
//  - w11|w21 -> int8 rows with per-row scale (wsc[n] = rowmax/127/15)
//  - w12/w22 -> bf16
//  - bias packing
// ---------------------------------------------------------------------------
__device__ __forceinline__ void split_state_perm(const float4* src, ushort4* dst,
                                                 int base, int t) {
#pragma unroll
    for (int p = 0; p < 4; p++) {
        const int i = base * 1024 + p * 256 + t;
        const float4 v = src[i];
        ushort4 h, l;
        h.x = f2bf(v.x); l.x = f2bf(v.x - bf2f(h.x));
        h.y = f2bf(v.y); l.y = f2bf(v.y - bf2f(h.y));
        h.z = f2bf(v.z); l.z = f2bf(v.z - bf2f(h.z));
        h.w = f2bf(v.w); l.w = f2bf(v.w - bf2f(h.w));
        const int s = i >> 7, c4 = i & 127;      // source row (b*5+f), f4-col
        const int b = s / 5, f = s - b * 5;
        const int m = ((b >> 5) * 160) + (((b >> 4) & 1) * 80) + (f << 4) + (b & 15);
        ushort4* row = dst + (size_t)m * 384;    // 1536 ushorts = 384 ushort4
        row[c4] = h; row[128 + c4] = h; row[256 + c4] = l;   // [hi|hi|lo]
    }
}
__device__ __forceinline__ void split_w_perm(const float4* src, ushort4* dst,
                                             int base, int t, int j) {
#pragma unroll
    for (int p = 0; p < 4; p++) {
        const int i = base * 1024 + p * 256 + t;
        const float4 v = src[i];
        ushort4 h, l;
        h.x = f2bf(v.x); l.x = f2bf(v.x - bf2f(h.x));
        h.y = f2bf(v.y); l.y = f2bf(v.y - bf2f(h.y));
        h.z = f2bf(v.z); l.z = f2bf(v.z - bf2f(h.z));
        h.w = f2bf(v.w); l.w = f2bf(v.w - bf2f(h.w));
        const int c = i >> 7, c4 = i & 127;      // source row (channel), f4-col
        const int n = ((c >> 6) * 192) + (((c >> 4) & 3) * 48) + (j << 4) + (c & 15);
        ushort4* row = dst + (size_t)n * 384;
        row[c4] = h; row[128 + c4] = l; row[256 + c4] = h;   // [hi|lo|hi]
    }
}
__device__ __forceinline__ void do_cvt4(const float4* src, ushort4* dst,
                                        int base, int t) {
#pragma unroll
    for (int p = 0; p < 4; p++) {
        const int i = base * 1024 + p * 256 + t;
        const float4 v = src[i];
        ushort4 h;
        h.x = f2bf(v.x); h.y = f2bf(v.y); h.z = f2bf(v.z); h.w = f2bf(v.w);
        dst[i] = h;
    }
}
__device__ __forceinline__ int q8(float x, float inv) {
    int q = (int)rintf(x * inv);
    q = q > 127 ? 127 : (q < -127 ? -127 : q);
    return q & 0xff;
}

__global__ __launch_bounds__(256) void prep_kernel(
    const float* __restrict__ state,
    const float* __restrict__ w1, const float* __restrict__ w2,
    const float* __restrict__ w3,
    const float* __restrict__ w11, const float* __restrict__ w21,
    const float* __restrict__ w12, const float* __restrict__ w22,
    const float* __restrict__ b1, const float* __restrict__ b2,
    const float* __restrict__ b3, const float* __restrict__ b11,
    const float* __restrict__ b21, const float* __restrict__ b12,
    const float* __restrict__ b22,
    ushort_t* __restrict__ Ap, ushort_t* __restrict__ Wp,
    signed char* __restrict__ w1q, float* __restrict__ wsc,
    ushort_t* __restrict__ w2b,
    float* __restrict__ b123, float* __restrict__ bb1, float* __restrict__ bb2)
{
    const int bid = blockIdx.x;
    const int t = threadIdx.x;
    if (bid < 1280) {
        split_state_perm((const float4*)state, (ushort4*)Ap, bid, t);
    } else if (bid < 1408) {
        split_w_perm((const float4*)w1, (ushort4*)Wp, bid - 1280, t, 0);
    } else if (bid < 1536) {
        split_w_perm((const float4*)w2, (ushort4*)Wp, bid - 1408, t, 1);
    } else if (bid < 1664) {
        split_w_perm((const float4*)w3, (ushort4*)Wp, bid - 1536, t, 2);
    } else if (bid < 3712) {
        // one block per output row of [w11 ; w21] -> int8 + per-row scale
        const int r = bid - 1664;
        const float* src = (r < 1024) ? (w11 + (size_t)r * 4096)
                                      : (w21 + (size_t)(r - 1024) * 4096);
        __shared__ float red[256];
        float4 v[4];
        float lmax = 0.f;
#pragma unroll
        for (int p = 0; p < 4; p++) {
            v[p] = ((const float4*)src)[t * 4 + p];
            lmax = fmaxf(lmax, fmaxf(fmaxf(fabsf(v[p].x), fabsf(v[p].y)),
                                     fmaxf(fabsf(v[p].z), fabsf(v[p].w))));
        }
        red[t] = lmax;
        __syncthreads();
        for (int s = 128; s > 0; s >>= 1) {
            if (t < s) red[t] = fmaxf(red[t], red[t + s]);
            __syncthreads();
        }
        const float gmax = fmaxf(red[0], 1e-30f);
        const float inv = 127.0f / gmax;
        int4 o;
        o.x = q8(v[0].x, inv) | (q8(v[0].y, inv) << 8) | (q8(v[0].z, inv) << 16) | (q8(v[0].w, inv) << 24);
        o.y = q8(v[1].x, inv) | (q8(v[1].y, inv) << 8) | (q8(v[1].z, inv) << 16) | (q8(v[1].w, inv) << 24);
        o.z = q8(v[2].x, inv) | (q8(v[2].y, inv) << 8) | (q8(v[2].z, inv) << 16) | (q8(v[2].w, inv) << 24);
        o.w = q8(v[3].x, inv) | (q8(v[3].y, inv) << 8) | (q8(v[3].z, inv) << 16) | (q8(v[3].w, inv) << 24);
        ((int4*)(w1q + (size_t)r * 4096))[t] = o;
        if (t == 0) wsc[r] = gmax / (127.0f * 15.0f);
    } else if (bid < 3968) {
        do_cvt4((const float4*)w12, (ushort4*)w2b, bid - 3712, t);
    } else if (bid < 4224) {
        do_cvt4((const float4*)w22, (ushort4*)(w2b + 1048576), bid - 3968, t);
    } else {
#pragma unroll
        for (int p = 0; p < 4; p++) {
            const int i = p * 256 + t;
            b123[i] = b1[i]; b123[1024 + i] = b2[i]; b123[2048 + i] = b3[i];
            bb1[i] = b11[i]; bb1[1024 + i] = b21[i];
            bb2[i] = b12[i]; bb2[1024 + i] = b22[i];
        }
    }
}

// ---------------------------------------------------------------------------
// Heads (both branches): out[b][n] = (clip?)(h2[b][off+k] . w[n][k] + bias[n])
// ---------------------------------------------------------------------------
__global__ __launch_bounds__(256) void head_kernel(
    const ushort_t* __restrict__ h, const float* __restrict__ wm,
    const float* __restrict__ bm, const float* __restrict__ ws,
    const float* __restrict__ bs, float* __restrict__ out)
{
    const int t = threadIdx.x;
    const int branch = blockIdx.x >> 8;
    const int n = t & 31;
    const int b = (blockIdx.x & 255) * 8 + (t >> 5);
    const ushort_t* hr = h + (size_t)b * 2048 + branch * 1024;
    const float* wr = (branch ? ws : wm) + (size_t)n * 1024;
    float s = 0.f;
#pragma unroll 4
    for (int k = 0; k < 1024; k += 8) {
        const uint4 hv = *(const uint4*)&hr[k];
        const float4 w0 = *(const float4*)&wr[k];
        const float4 w1 = *(const float4*)&wr[k + 4];
        s += blo(hv.x) * w0.x + bhi(hv.x) * w0.y
           + blo(hv.y) * w0.z + bhi(hv.y) * w0.w
           + blo(hv.z) * w1.x + bhi(hv.z) * w1.y
           + blo(hv.w) * w1.z + bhi(hv.w) * w1.w;
    }
    s += (branch ? bs : bm)[n];
    if (branch) s = fminf(fmaxf(s, -20.f), 2.f);
    out[(size_t)branch * 65536 + (size_t)b * 32 + n] = s;
}

// ---------------------------------------------------------------------------
extern "C" void kernel_launch(void* const* d_in, const int* in_sizes, int n_in,
                              void* d_out, int out_size, void* d_ws, size_t ws_size,
                              hipStream_t stream)
{
    const float* state = (const float*)d_in[0];
    const float* w1  = (const float*)d_in[1];  const float* b1  = (const float*)d_in[2];
    const float* w2  = (const float*)d_in[3];  const float* b2  = (const float*)d_in[4];
    const float* w3  = (const float*)d_in[5];  const float* b3  = (const float*)d_in[6];
    const float* wl  = (const float*)d_in[7];  const float* bl  = (const float*)d_in[8];
    const float* w11 = (const float*)d_in[9];  const float* b11 = (const float*)d_in[10];
    const float* w12 = (const float*)d_in[11]; const float* b12 = (const float*)d_in[12];
    const float* w21 = (const float*)d_in[13]; const float* b21 = (const float*)d_in[14];
    const float* w22 = (const float*)d_in[15]; const float* b22 = (const float*)d_in[16];
    const float* wm  = (const float*)d_in[17]; const float* bm  = (const float*)d_in[18];
    const float* ws  = (const float*)d_in[19]; const float* bs  = (const float*)d_in[20];
    float* out = (float*)d_out;

    // ---- workspace layout ----
    char* wp = (char*)d_ws;
    ushort_t*    Ap    = (ushort_t*)wp;    wp += (size_t)10240 * 1536 * 2;   // 31.5MB
    ushort_t*    Wp    = (ushort_t*)wp;    wp += (size_t)3072 * 1536 * 2;    // 9.4MB
    signed char* xb    = (signed char*)wp; wp += (size_t)2048 * 4096;        // int8 counts
    signed char* w1q   = (signed char*)wp; wp += (size_t)2048 * 4096;        // int8 [w11;w21]
    ushort_t*    w2b   = (ushort_t*)wp;    wp += (size_t)2048 * 1024 * 2;
    ushort_t*    h1    = (ushort_t*)wp;    wp += (size_t)2048 * 2048 * 2;
    ushort_t*    h2    = (ushort_t*)wp;    wp += (size_t)2048 * 2048 * 2;
    float*       wsc   = (float*)wp;       wp += 2048 * 4;
    float*       b123  = (float*)wp;       wp += 3072 * 4;
    float*       bb1   = (float*)wp;       wp += 2048 * 4;
    float*       bb2   = (float*)wp;       wp += 2048 * 4;

    // ---- prep: permuted splits, int8 quant, cvts, bias packing ----
    prep_kernel<<<4225, 256, 0, stream>>>(
        state, w1, w2, w3, w11, w21, w12, w22,
        b1, b2, b3, b11, b21, b12, b22,
        Ap, Wp, w1q, wsc, w2b, b123, bb1, bb2);

    // ---- fused currents GEMM + LIF -> spike counts int8 [2048, 4096] ----
    fused_cur_lif<<<dim3(64, 16), 512, 0, stream>>>(Ap, Wp, b123, wl, bl, xb);

    // ---- MLP layer 1 (both branches) i8 K=64 MFMA, 512 blocks ----
    mlp1_i8<<<dim3(32, 16), 256, 0, stream>>>(xb, w1q, wsc, bb1, h1);

    // ---- MLP layer 2 (block-diagonal) bf16, 512 blocks ----
    mlp2_bf16<<<dim3(32, 16), 256, 0, stream>>>(
        h1, w2b, bb2, h2, 2048, 1024, 2048, 1024, 2048, 1024);

    // ---- heads (both branches) ----
    head_kernel<<<512, 256, 0, stream>>>(h2, wm, bm, ws, bs, out);
}

// Round 5
// 365.101 us; speedup vs baseline: 1.0586x; 1.0137x over previous
//
#include <hip/hip_runtime.h>
#include <cstddef>
#include <cstdint>

#define THRESH 0.8f
#define DECAY  0.2f

typedef unsigned short ushort_t;
typedef __attribute__((ext_vector_type(8))) short bf16x8;
typedef __attribute__((ext_vector_type(4))) float f32x4;
typedef __attribute__((ext_vector_type(4))) int i32x4;   // also 16 x i8 operand

__device__ __forceinline__ ushort_t f2bf(float f) {
    union { float f; unsigned u; } v; v.f = f;
    unsigned r = v.u + 0x7FFFu + ((v.u >> 16) & 1u);
    return (ushort_t)(r >> 16);
}
__device__ __forceinline__ float bf2f(ushort_t h) {
    union { unsigned u; float f; } v; v.u = ((unsigned)h) << 16;
    return v.f;
}
__device__ __forceinline__ float blo(unsigned u) {
    union { unsigned x; float f; } v; v.x = u << 16; return v.f;
}
__device__ __forceinline__ float bhi(unsigned u) {
    union { unsigned x; float f; } v; v.x = u & 0xFFFF0000u; return v.f;
}

// async global->LDS, 16B per lane; LDS dest = wave-uniform base + lane*16
__device__ __forceinline__ void gload16(const void* g, void* l) {
    __builtin_amdgcn_global_load_lds(
        (const __attribute__((address_space(1))) void*)g,
        (__attribute__((address_space(3))) void*)l,
        16, 0, 0);
}

// compiler-invisible LDS read (keeps waitcnt control out of the compiler)
#define DSREAD(dst, addr, off) \
    asm volatile("ds_read_b128 %0, %1 offset:" #off : "=v"(dst) : "v"(addr))

#define MM(i, j, a, w) \
    acc[i][j] = __builtin_amdgcn_mfma_f32_16x16x32_bf16(a, w, acc[i][j], 0, 0, 0)

// ---------------------------------------------------------------------------
// Fused currents-GEMM + LIF recurrence (structure identical to R4; K-loop
// FULLY UNROLLED so all addresses are compile-time: global staging offsets
// fold into global_load_lds' 13-bit offset field (max 3008B < 4096), LDS
// read bases are 3 precomputed VGPRs (av0-2/bv0-2) with literal offset:
// tokens, buffer rotation tt%3 folds.  Targets R4's measured VALUBusy=36%
// (per-iter address VALU ~= MFMA time).  Pipeline semantics unchanged:
// 3 buffers, prefetch distance 2, per-wave counted vmcnt (4/8 steady),
// 2 barriers/tile, asm ds_reads + lgkmcnt(0)+sched_barrier fences, setprio.
// ---------------------------------------------------------------------------
__global__ __launch_bounds__(512, 4) void fused_cur_lif(
    const ushort_t* __restrict__ A, const ushort_t* __restrict__ W,
    const float* __restrict__ b123, const float* __restrict__ wl,
    const float* __restrict__ bl, signed char* __restrict__ xb)
{
    // [buf][ A: 160x32 (5120 us) | B: 192x32 (6144 us) ] = 22.5KB x 3
    __shared__ ushort_t lds[3][11264];

    const int t = threadIdx.x;
    const int bx = blockIdx.x;           // 0..63  (m: 32 batches each)
    const int by = blockIdx.y;           // 0..15  (n: 64 channels each)
    const int lane = t & 63;
    const int wv = t >> 6;
    const int wm = (wv >> 2) * 80;       // wave m-offset: 0 / 80
    const int wn = (wv & 3) * 48;        // wave n-offset: 0/48/96/144
    const int fr = lane & 15;
    const int fq = lane >> 4;
    const int swz16 = (fq ^ ((fr >> 1) & 3)) * 16;   // read swizzle, bytes

    // per-buffer ds_read base addresses (bytes); buffer stride 22528
    const unsigned av0 = (unsigned)((wm + fr) * 64 + swz16);
    const unsigned av1 = av0 + 22528;
    const unsigned av2 = av0 + 45056;
    const unsigned bv0 = (unsigned)(10240 + (wn + fr) * 64 + swz16);
    const unsigned bv1 = bv0 + 22528;
    const unsigned bv2 = bv0 + 45056;

    // staging role: waves 0-4 stage A (2 x 16-row groups), 5-7 stage B (4)
    const ushort_t* src0; const ushort_t* src1;
    const ushort_t* src2; const ushort_t* src3;
    int dst0, dst1, dst2, dst3;
    if (wv < 5) {
        const int rl0 = wv * 32 + (lane >> 2);
        const int rl1 = rl0 + 16;
        src0 = A + (size_t)(bx * 160 + rl0) * 1536 + ((lane & 3) ^ ((rl0 >> 1) & 3)) * 8;
        src1 = A + (size_t)(bx * 160 + rl1) * 1536 + ((lane & 3) ^ ((rl1 >> 1) & 3)) * 8;
        src2 = src0; src3 = src1;
        dst0 = rl0 * 32 + (lane & 3) * 8;
        dst1 = rl1 * 32 + (lane & 3) * 8;
        dst2 = dst0; dst3 = dst1;
    } else {
        const int rb = (wv - 5) * 64 + (lane >> 2);
        src0 = W + (size_t)(by * 192 + rb) * 1536 + ((lane & 3) ^ ((rb >> 1) & 3)) * 8;
        src1 = src0 + (size_t)16 * 1536;
        src2 = src0 + (size_t)32 * 1536;
        src3 = src0 + (size_t)48 * 1536;
        dst0 = 5120 + rb * 32 + (lane & 3) * 8;
        dst1 = dst0 + 16 * 32;
        dst2 = dst0 + 32 * 32;
        dst3 = dst0 + 48 * 32;
    }

#define STAGE(tile, sbuf)                                              \
    do {                                                               \
        ushort_t* lb_ = &lds[sbuf][0];                                 \
        if (wv < 5) {                                                  \
            gload16(src0 + (tile) * 32, lb_ + dst0);                   \
            gload16(src1 + (tile) * 32, lb_ + dst1);                   \
        } else {                                                       \
            gload16(src0 + (tile) * 32, lb_ + dst0);                   \
            gload16(src1 + (tile) * 32, lb_ + dst1);                   \
            gload16(src2 + (tile) * 32, lb_ + dst2);                   \
            gload16(src3 + (tile) * 32, lb_ + dst3);                   \
        }                                                              \
    } while (0)

#define COMPUTE(av_, bv_)                                              \
    do {                                                               \
        bf16x8 af0, af1, af2, af3, af4, wf0, wf1, wf2;                 \
        DSREAD(af0, av_, 0);                                           \
        DSREAD(af1, av_, 1024);                                        \
        DSREAD(af2, av_, 2048);                                        \
        DSREAD(af3, av_, 3072);                                        \
        DSREAD(af4, av_, 4096);                                        \
        DSREAD(wf0, bv_, 0);                                           \
        DSREAD(wf1, bv_, 1024);                                        \
        DSREAD(wf2, bv_, 2048);                                        \
        asm volatile("s_waitcnt lgkmcnt(0)" ::: "memory");             \
        __builtin_amdgcn_sched_barrier(0);                             \
        __builtin_amdgcn_s_setprio(1);                                 \
        MM(0, 0, af0, wf0); MM(0, 1, af0, wf1); MM(0, 2, af0, wf2);    \
        MM(1, 0, af1, wf0); MM(1, 1, af1, wf1); MM(1, 2, af1, wf2);    \
        MM(2, 0, af2, wf0); MM(2, 1, af2, wf1); MM(2, 2, af2, wf2);    \
        MM(3, 0, af3, wf0); MM(3, 1, af3, wf1); MM(3, 2, af3, wf2);    \
        MM(4, 0, af4, wf0); MM(4, 1, af4, wf1); MM(4, 2, af4, wf2);    \
        __builtin_amdgcn_s_setprio(0);                                 \
    } while (0)

    f32x4 acc[5][3];
#pragma unroll
    for (int i = 0; i < 5; i++)
#pragma unroll
        for (int j = 0; j < 3; j++) {
            f32x4 z = {0.f, 0.f, 0.f, 0.f};
            acc[i][j] = z;
        }

    // prologue: tiles 0,1 in flight
    STAGE(0, 0);
    STAGE(1, 1);

    // main loop, fully unrolled: tiles 0..45, staging 2..47
#pragma unroll
    for (int tt = 0; tt < 46; ++tt) {
        STAGE(tt + 2, (tt + 2) % 3);
        if (wv < 5) asm volatile("s_waitcnt vmcnt(4)" ::: "memory");
        else        asm volatile("s_waitcnt vmcnt(8)" ::: "memory");
        __builtin_amdgcn_s_barrier();
        __builtin_amdgcn_sched_barrier(0);
        const unsigned av_ = (tt % 3 == 0) ? av0 : (tt % 3 == 1) ? av1 : av2;
        const unsigned bv_ = (tt % 3 == 0) ? bv0 : (tt % 3 == 1) ? bv1 : bv2;
        COMPUTE(av_, bv_);
        __builtin_amdgcn_s_barrier();
        __builtin_amdgcn_sched_barrier(0);
    }
    // tt = 46 (buffer 1): only tile 47's loads still outstanding
    if (wv < 5) asm volatile("s_waitcnt vmcnt(2)" ::: "memory");
    else        asm volatile("s_waitcnt vmcnt(4)" ::: "memory");
    __builtin_amdgcn_s_barrier();
    __builtin_amdgcn_sched_barrier(0);
    COMPUTE(av1, bv1);
    __builtin_amdgcn_s_barrier();
    __builtin_amdgcn_sched_barrier(0);
    // tt = 47 (buffer 2): drain
    asm volatile("s_waitcnt vmcnt(0)" ::: "memory");
    __builtin_amdgcn_s_barrier();
    __builtin_amdgcn_sched_barrier(0);
    COMPUTE(av2, bv2);
#undef STAGE
#undef COMPUTE

    // ---- epilogue: in-register LIF recurrence (replaces recur_kernel) ----
    // lane holds: batches bbase+r (r=0..3), channel ch; acc[f][j][r] = the
    // current of matrix j (w1/w2/w3), frame f, batch r.
    const int ch = by * 64 + (wv & 3) * 16 + fr;
    const float b1c = b123[ch];
    const float b2c = b123[1024 + ch];
    const float b3c = b123[2048 + ch];
    const float wl0 = wl[0], wl1 = wl[1], wl2 = wl[2], bl0 = bl[0];
    const int bbase = bx * 32 + (wv >> 2) * 16 + fq * 4;
#pragma unroll
    for (int r = 0; r < 4; r++) {
        float m0 = 0.f, m1 = 0.f, m2 = 0.f, m3 = 0.f;
        int s0 = 0, s1 = 0, s2 = 0, s3 = 0;
#pragma unroll
        for (int f = 0; f < 5; f++) {
            const float i1 = acc[f][0][r] + b1c;
            const float i2 = acc[f][1][r] + b2c;
            const float i3 = acc[f][2][r] + b3c;
#pragma unroll
            for (int rep = 0; rep < 3; rep++) {
                const float inner = m0 * wl0 + m1 * wl1 + m2 * wl2 + bl0;
                const float n0 = i1 + ((m0 > THRESH) ? 0.f : DECAY * m0);
                const float n1 = i2 + ((m1 > THRESH) ? 0.f : DECAY * m1);
                const float n2 = i3 + ((m2 > THRESH) ? 0.f : DECAY * m2);
                const float n3 = inner + ((m3 > THRESH) ? 0.f : DECAY * m3);
                m0 = n0; m1 = n1; m2 = n2; m3 = n3;
                s0 += (n0 > THRESH); s1 += (n1 > THRESH);
                s2 += (n2 > THRESH); s3 += (n3 > THRESH);
            }
        }
        uchar4 o;
        o.x = (unsigned char)s0; o.y = (unsigned char)s1;
        o.z = (unsigned char)s2; o.w = (unsigned char)s3;
        *(uchar4*)&xb[(size_t)(bbase + r) * 4096 + ch * 4] = o;
    }
}

// ---------------------------------------------------------------------------
// MLP layer 1, int8 MFMA at FULL rate (16x16x64, 16B frags):
// A = spike counts 0..15 (exact in i8), W = per-row-quantized int8.
// 64x128 tile, 256 threads = 4 waves side-by-side in n (per-wave 64x32,
// acc[4][2]).  BK=64 bytes.  Chunk swizzle (16B chunks).
// Direct epilogue: fp32(acc)*wsc[col] + bias[col], relu, bf16.
// ---------------------------------------------------------------------------
__global__ __launch_bounds__(256) void mlp1_i8(
    const signed char* __restrict__ A, const signed char* __restrict__ W,
    const float* __restrict__ wsc, const float* __restrict__ bias,
    ushort_t* __restrict__ C)
{
    __shared__ signed char sA[64 * 64];    // 4 KB
    __shared__ signed char sW[128 * 64];   // 8 KB

    const int t = threadIdx.x;
    const int mBase = blockIdx.x * 64;
    const int nBase = blockIdx.y * 128;

    const int lane = t & 63;
    const int wv = t >> 6;
    const int wn = wv * 32;
    const int fr = lane & 15;
    const int fq = lane >> 4;            // k-offset = fq*16 bytes
    const int fsw = (fq ^ ((fr >> 1) & 3)) * 16;  // swizzled read chunk (bytes)

    const int r0 = t >> 2;                           // staging row 0..63
    const int cc = ((t & 3) ^ ((t >> 3) & 3)) * 16;  // pre-swizzled src byte-col

    i32x4 acc[4][2];
#pragma unroll
    for (int i = 0; i < 4; i++)
#pragma unroll
        for (int j = 0; j < 2; j++) {
            i32x4 z = {0, 0, 0, 0};
            acc[i][j] = z;
        }

    for (int k0 = 0; k0 < 4096; k0 += 64) {
        gload16(&A[(size_t)(mBase + r0) * 4096 + k0 + cc], &sA[t * 16]);
        gload16(&W[(size_t)(nBase + r0) * 4096 + k0 + cc], &sW[t * 16]);
        gload16(&W[(size_t)(nBase + 64 + r0) * 4096 + k0 + cc], &sW[4096 + t * 16]);
        __syncthreads();

        i32x4 af[4], wf[2];
#pragma unroll
        for (int i = 0; i < 4; i++)
            af[i] = *(const i32x4*)&sA[(i * 16 + fr) * 64 + fsw];
#pragma unroll
        for (int j = 0; j < 2; j++)
            wf[j] = *(const i32x4*)&sW[(wn + j * 16 + fr) * 64 + fsw];
#pragma unroll
        for (int i = 0; i < 4; i++)
#pragma unroll
            for (int j = 0; j < 2; j++)
                acc[i][j] = __builtin_amdgcn_mfma_i32_16x16x64_i8(af[i], wf[j], acc[i][j], 0, 0, 0);
        __syncthreads();
    }

#pragma unroll
    for (int j = 0; j < 2; j++) {
        const int col = nBase + wn + j * 16 + fr;
        const float sc = wsc[col];
        const float bv = bias[col];
#pragma unroll
        for (int i = 0; i < 4; i++)
#pragma unroll
            for (int r = 0; r < 4; r++) {
                const int row = mBase + i * 16 + fq * 4 + r;
                const float v = (float)acc[i][j][r] * sc + bv;
                C[(size_t)row * 2048 + col] = f2bf(fmaxf(v, 0.f));
            }
    }
}

// ---------------------------------------------------------------------------
// MLP layer 2: bf16, 64x128 tile, 4 waves side-by-side in n (per-wave 64x32),
// BK=32, grid 32x16 = 512 blocks, direct epilogue (bias+relu+bf16).
// Block-diagonal: upper n-half reads A columns at +aHalfOff.
// ---------------------------------------------------------------------------
__global__ __launch_bounds__(256) void mlp2_bf16(
    const ushort_t* __restrict__ A, const ushort_t* __restrict__ W,
    const float* __restrict__ bias, ushort_t* __restrict__ C,
    int N, int K, int lda, int ldw, int ldc, int aHalfOff)
{
    __shared__ ushort_t sA[64 * 32];
    __shared__ ushort_t sW[128 * 32];

    const int t = threadIdx.x;
    const int mBase = blockIdx.x * 64;
    const int nBase = blockIdx.y * 128;
    const int aOff = (2 * nBase >= N) ? aHalfOff : 0;

    const int lane = t & 63;
    const int wv = t >> 6;
    const int wn = wv * 32;
    const int fr = lane & 15;
    const int fq = lane >> 4;
    const int fsw = (fq ^ ((fr >> 1) & 3)) * 8;   // swizzled read chunk (ushorts)

    const int r0 = t >> 2;                           // 0..63
    const int cc = ((t & 3) ^ ((t >> 3) & 3)) * 8;   // pre-swizzled src k-col

    f32x4 acc[4][2];
#pragma unroll
    for (int i = 0; i < 4; i++)
#pragma unroll
        for (int j = 0; j < 2; j++) {
            f32x4 z = {0.f, 0.f, 0.f, 0.f};
            acc[i][j] = z;
        }

    for (int k0 = 0; k0 < K; k0 += 32) {
        gload16(&A[(size_t)(mBase + r0) * lda + aOff + k0 + cc], &sA[t * 8]);
        gload16(&W[(size_t)(nBase + r0) * ldw + k0 + cc], &sW[t * 8]);
        gload16(&W[(size_t)(nBase + 64 + r0) * ldw + k0 + cc], &sW[2048 + t * 8]);
        __syncthreads();

        bf16x8 af[4], wf[2];
#pragma unroll
        for (int i = 0; i < 4; i++)
            af[i] = *(const bf16x8*)&sA[(i * 16 + fr) * 32 + fsw];
#pragma unroll
        for (int j = 0; j < 2; j++)
            wf[j] = *(const bf16x8*)&sW[(wn + j * 16 + fr) * 32 + fsw];
#pragma unroll
        for (int i = 0; i < 4; i++)
#pragma unroll
            for (int j = 0; j < 2; j++)
                acc[i][j] = __builtin_amdgcn_mfma_f32_16x16x32_bf16(af[i], wf[j], acc[i][j], 0, 0, 0);
        __syncthreads();
    }

#pragma unroll
    for (int j = 0; j < 2; j++) {
        const int col = nBase + wn + j * 16 + fr;
        const float bv = bias[col];
#pragma unroll
        for (int i = 0; i < 4; i++)
#pragma unroll
            for (int r = 0; r < 4; r++) {
                const int row = mBase + i * 16 + fq * 4 + r;
                C[(size_t)row * ldc + col] = f2bf(fmaxf(acc[i][j][r] + bv, 0.f));
            }
    }
}

// ---------------------------------------------------------------------------
// Consolidated prep:
//  - state -> A'' (row-permuted, K-concat [hi|hi|lo])
//  - w1/w2/w3 -> W'' (row-permuted, K-concat [hi|lo|hi])
//  - w11|w21 -> int8 rows with per-row scale (wsc[n] = rowmax/127/15)
//  - w12/w22 -> bf16
//  - bias packing
// ---------------------------------------------------------------------------
__device__ __forceinline__ void split_state_perm(const float4* src, ushort4* dst,
                                                 int base, int t) {
#pragma unroll
    for (int p = 0; p < 4; p++) {
        const int i = base * 1024 + p * 256 + t;
        const float4 v = src[i];
        ushort4 h, l;
        h.x = f2bf(v.x); l.x = f2bf(v.x - bf2f(h.x));
        h.y = f2bf(v.y); l.y = f2bf(v.y - bf2f(h.y));
        h.z = f2bf(v.z); l.z = f2bf(v.z - bf2f(h.z));
        h.w = f2bf(v.w); l.w = f2bf(v.w - bf2f(h.w));
        const int s = i >> 7, c4 = i & 127;      // source row (b*5+f), f4-col
        const int b = s / 5, f = s - b * 5;
        const int m = ((b >> 5) * 160) + (((b >> 4) & 1) * 80) + (f << 4) + (b & 15);
        ushort4* row = dst + (size_t)m * 384;    // 1536 ushorts = 384 ushort4
        row[c4] = h; row[128 + c4] = h; row[256 + c4] = l;   // [hi|hi|lo]
    }
}
__device__ __forceinline__ void split_w_perm(const float4* src, ushort4* dst,
                                             int base, int t, int j) {
#pragma unroll
    for (int p = 0; p < 4; p++) {
        const int i = base * 1024 + p * 256 + t;
        const float4 v = src[i];
        ushort4 h, l;
        h.x = f2bf(v.x); l.x = f2bf(v.x - bf2f(h.x));
        h.y = f2bf(v.y); l.y = f2bf(v.y - bf2f(h.y));
        h.z = f2bf(v.z); l.z = f2bf(v.z - bf2f(h.z));
        h.w = f2bf(v.w); l.w = f2bf(v.w - bf2f(h.w));
        const int c = i >> 7, c4 = i & 127;      // source row (channel), f4-col
        const int n = ((c >> 6) * 192) + (((c >> 4) & 3) * 48) + (j << 4) + (c & 15);
        ushort4* row = dst + (size_t)n * 384;
        row[c4] = h; row[128 + c4] = l; row[256 + c4] = h;   // [hi|lo|hi]
    }
}
__device__ __forceinline__ void do_cvt4(const float4* src, ushort4* dst,
                                        int base, int t) {
#pragma unroll
    for (int p = 0; p < 4; p++) {
        const int i = base * 1024 + p * 256 + t;
        const float4 v = src[i];
        ushort4 h;
        h.x = f2bf(v.x); h.y = f2bf(v.y); h.z = f2bf(v.z); h.w = f2bf(v.w);
        dst[i] = h;
    }
}
__device__ __forceinline__ int q8(float x, float inv) {
    int q = (int)rintf(x * inv);
    q = q > 127 ? 127 : (q < -127 ? -127 : q);
    return q & 0xff;
}

__global__ __launch_bounds__(256) void prep_kernel(
    const float* __restrict__ state,
    const float* __restrict__ w1, const float* __restrict__ w2,
    const float* __restrict__ w3,
    const float* __restrict__ w11, const float* __restrict__ w21,
    const float* __restrict__ w12, const float* __restrict__ w22,
    const float* __restrict__ b1, const float* __restrict__ b2,
    const float* __restrict__ b3, const float* __restrict__ b11,
    const float* __restrict__ b21, const float* __restrict__ b12,
    const float* __restrict__ b22,
    ushort_t* __restrict__ Ap, ushort_t* __restrict__ Wp,
    signed char* __restrict__ w1q, float* __restrict__ wsc,
    ushort_t* __restrict__ w2b,
    float* __restrict__ b123, float* __restrict__ bb1, float* __restrict__ bb2)
{
    const int bid = blockIdx.x;
    const int t = threadIdx.x;
    if (bid < 1280) {
        split_state_perm((const float4*)state, (ushort4*)Ap, bid, t);
    } else if (bid < 1408) {
        split_w_perm((const float4*)w1, (ushort4*)Wp, bid - 1280, t, 0);
    } else if (bid < 1536) {
        split_w_perm((const float4*)w2, (ushort4*)Wp, bid - 1408, t, 1);
    } else if (bid < 1664) {
        split_w_perm((const float4*)w3, (ushort4*)Wp, bid - 1536, t, 2);
    } else if (bid < 3712) {
        // one block per output row of [w11 ; w21] -> int8 + per-row scale
        const int r = bid - 1664;
        const float* src = (r < 1024) ? (w11 + (size_t)r * 4096)
                                      : (w21 + (size_t)(r - 1024) * 4096);
        __shared__ float red[256];
        float4 v[4];
        float lmax = 0.f;
#pragma unroll
        for (int p = 0; p < 4; p++) {
            v[p] = ((const float4*)src)[t * 4 + p];
            lmax = fmaxf(lmax, fmaxf(fmaxf(fabsf(v[p].x), fabsf(v[p].y)),
                                     fmaxf(fabsf(v[p].z), fabsf(v[p].w))));
        }
        red[t] = lmax;
        __syncthreads();
        for (int s = 128; s > 0; s >>= 1) {
            if (t < s) red[t] = fmaxf(red[t], red[t + s]);
            __syncthreads();
        }
        const float gmax = fmaxf(red[0], 1e-30f);
        const float inv = 127.0f / gmax;
        int4 o;
        o.x = q8(v[0].x, inv) | (q8(v[0].y, inv) << 8) | (q8(v[0].z, inv) << 16) | (q8(v[0].w, inv) << 24);
        o.y = q8(v[1].x, inv) | (q8(v[1].y, inv) << 8) | (q8(v[1].z, inv) << 16) | (q8(v[1].w, inv) << 24);
        o.z = q8(v[2].x, inv) | (q8(v[2].y, inv) << 8) | (q8(v[2].z, inv) << 16) | (q8(v[2].w, inv) << 24);
        o.w = q8(v[3].x, inv) | (q8(v[3].y, inv) << 8) | (q8(v[3].z, inv) << 16) | (q8(v[3].w, inv) << 24);
        ((int4*)(w1q + (size_t)r * 4096))[t] = o;
        if (t == 0) wsc[r] = gmax / (127.0f * 15.0f);
    } else if (bid < 3968) {
        do_cvt4((const float4*)w12, (ushort4*)w2b, bid - 3712, t);
    } else if (bid < 4224) {
        do_cvt4((const float4*)w22, (ushort4*)(w2b + 1048576), bid - 3968, t);
    } else {
#pragma unroll
        for (int p = 0; p < 4; p++) {
            const int i = p * 256 + t;
            b123[i] = b1[i]; b123[1024 + i] = b2[i]; b123[2048 + i] = b3[i];
            bb1[i] = b11[i]; bb1[1024 + i] = b21[i];
            bb2[i] = b12[i]; bb2[1024 + i] = b22[i];
        }
    }
}

// ---------------------------------------------------------------------------
// Heads (both branches): out[b][n] = (clip?)(h2[b][off+k] . w[n][k] + bias[n])
// ---------------------------------------------------------------------------
__global__ __launch_bounds__(256) void head_kernel(
    const ushort_t* __restrict__ h, const float* __restrict__ wm,
    const float* __restrict__ bm, const float* __restrict__ ws,
    const float* __restrict__ bs, float* __restrict__ out)
{
    const int t = threadIdx.x;
    const int branch = blockIdx.x >> 8;
    const int n = t & 31;
    const int b = (blockIdx.x & 255) * 8 + (t >> 5);
    const ushort_t* hr = h + (size_t)b * 2048 + branch * 1024;
    const float* wr = (branch ? ws : wm) + (size_t)n * 1024;
    float s = 0.f;
#pragma unroll 4
    for (int k = 0; k < 1024; k += 8) {
        const uint4 hv = *(const uint4*)&hr[k];
        const float4 w0 = *(const float4*)&wr[k];
        const float4 w1 = *(const float4*)&wr[k + 4];
        s += blo(hv.x) * w0.x + bhi(hv.x) * w0.y
           + blo(hv.y) * w0.z + bhi(hv.y) * w0.w
           + blo(hv.z) * w1.x + bhi(hv.z) * w1.y
           + blo(hv.w) * w1.z + bhi(hv.w) * w1.w;
    }
    s += (branch ? bs : bm)[n];
    if (branch) s = fminf(fmaxf(s, -20.f), 2.f);
    out[(size_t)branch * 65536 + (size_t)b * 32 + n] = s;
}

// ---------------------------------------------------------------------------
extern "C" void kernel_launch(void* const* d_in, const int* in_sizes, int n_in,
                              void* d_out, int out_size, void* d_ws, size_t ws_size,
                              hipStream_t stream)
{
    const float* state = (const float*)d_in[0];
    const float* w1  = (const float*)d_in[1];  const float* b1  = (const float*)d_in[2];
    const float* w2  = (const float*)d_in[3];  const float* b2  = (const float*)d_in[4];
    const float* w3  = (const float*)d_in[5];  const float* b3  = (const float*)d_in[6];
    const float* wl  = (const float*)d_in[7];  const float* bl  = (const float*)d_in[8];
    const float* w11 = (const float*)d_in[9];  const float* b11 = (const float*)d_in[10];
    const float* w12 = (const float*)d_in[11]; const float* b12 = (const float*)d_in[12];
    const float* w21 = (const float*)d_in[13]; const float* b21 = (const float*)d_in[14];
    const float* w22 = (const float*)d_in[15]; const float* b22 = (const float*)d_in[16];
    const float* wm  = (const float*)d_in[17]; const float* bm  = (const float*)d_in[18];
    const float* ws  = (const float*)d_in[19]; const float* bs  = (const float*)d_in[20];
    float* out = (float*)d_out;

    // ---- workspace layout ----
    char* wp = (char*)d_ws;
    ushort_t*    Ap    = (ushort_t*)wp;    wp += (size_t)10240 * 1536 * 2;   // 31.5MB
    ushort_t*    Wp    = (ushort_t*)wp;    wp += (size_t)3072 * 1536 * 2;    // 9.4MB
    signed char* xb    = (signed char*)wp; wp += (size_t)2048 * 4096;        // int8 counts
    signed char* w1q   = (signed char*)wp; wp += (size_t)2048 * 4096;        // int8 [w11;w21]
    ushort_t*    w2b   = (ushort_t*)wp;    wp += (size_t)2048 * 1024 * 2;
    ushort_t*    h1    = (ushort_t*)wp;    wp += (size_t)2048 * 2048 * 2;
    ushort_t*    h2    = (ushort_t*)wp;    wp += (size_t)2048 * 2048 * 2;
    float*       wsc   = (float*)wp;       wp += 2048 * 4;
    float*       b123  = (float*)wp;       wp += 3072 * 4;
    float*       bb1   = (float*)wp;       wp += 2048 * 4;
    float*       bb2   = (float*)wp;       wp += 2048 * 4;

    // ---- prep: permuted splits, int8 quant, cvts, bias packing ----
    prep_kernel<<<4225, 256, 0, stream>>>(
        state, w1, w2, w3, w11, w21, w12, w22,
        b1, b2, b3, b11, b21, b12, b22,
        Ap, Wp, w1q, wsc, w2b, b123, bb1, bb2);

    // ---- fused currents GEMM + LIF -> spike counts int8 [2048, 4096] ----
    fused_cur_lif<<<dim3(64, 16), 512, 0, stream>>>(Ap, Wp, b123, wl, bl, xb);

    // ---- MLP layer 1 (both branches) i8 K=64 MFMA, 512 blocks ----
    mlp1_i8<<<dim3(32, 16), 256, 0, stream>>>(xb, w1q, wsc, bb1, h1);

    // ---- MLP layer 2 (block-diagonal) bf16, 512 blocks ----
    mlp2_bf16<<<dim3(32, 16), 256, 0, stream>>>(
        h1, w2b, bb2, h2, 2048, 1024, 2048, 1024, 2048, 1024);

    // ---- heads (both branches) ----
    head_kernel<<<512, 256, 0, stream>>>(h2, wm, bm, ws, bs, out);
}